// Round 1
// 130.456 us; speedup vs baseline: 1.0056x; 1.0056x over previous
//
#include <hip/hip_runtime.h>
#include <math.h>

#define M 1024

#define TI 32
#define KCH 32
#define KSPLIT 16
#define KB (M / KSPLIT)   // 64 k's per block

// grid (32, 2, 16). qset 0: Q1 = A1*(p.C1). qset 1: Q2 = A2*(p.C2) AND Q3 = A2*(p.C3)
// (reference uses A2 for Q3!). A2 tile is loaded ONCE for both products.
// Also zero-fills the 8 MB output (spread across all 1024 blocks).
__global__ __launch_bounds__(256)
void diagq_kernel(const float* __restrict__ A1, const float* __restrict__ C1,
                  const float* __restrict__ A2, const float* __restrict__ C2,
                  const float* __restrict__ C3, const float* __restrict__ p1,
                  float* __restrict__ D /* [6][KSPLIT][M] */,
                  float* __restrict__ out /* zero-filled here */)
{
    __shared__ float As_re[TI][KCH + 1];
    __shared__ float As_im[TI][KCH + 1];
    __shared__ float Cb_re[KCH][TI + 1];   // +1 pad: kills 8-way write conflict
    __shared__ float Cb_im[KCH][TI + 1];
    __shared__ float Cc_re[KCH][TI + 1];
    __shared__ float Cc_im[KCH][TI + 1];
    __shared__ float red[4][256];

    const int t    = threadIdx.x;
    const int i0   = blockIdx.x * TI;
    const int qset = blockIdx.y;           // 0: A1/C1 ; 1: A2/{C2,C3}
    const int z    = blockIdx.z;
    const int k0   = z * KB;

    // ---- zero-fill our 8 KB slice of out (poisoned 0xAA each call) ----
    {
        const int bid = blockIdx.x + 32 * (blockIdx.y + 2 * blockIdx.z);  // 0..1023
        float4* o4 = (float4*)out + (size_t)bid * 512 + t;
        const float4 z4 = make_float4(0.f, 0.f, 0.f, 0.f);
        o4[0]   = z4;
        o4[256] = z4;
    }

    const float* __restrict__ A  = qset ? A2 : A1;
    const float* __restrict__ Cb = qset ? C2 : C1;

    const size_t MM = (size_t)M * M;

    // loader mapping: 8 threads/row, float4 each -> 128 B contiguous per 8 lanes
    const int l_row = t >> 3;          // 0..31
    const int l_c4  = (t & 7) << 2;    // 0,4,...,28

    // compute mapping
    const int i_local = t & 31;
    const int kslice  = t >> 5;        // 0..7, each covers 4 k's

    float b_re = 0.f, b_im = 0.f;      // acc for A*Cb
    float c_re_acc = 0.f, c_im_acc = 0.f;  // acc for A*Cc (qset==1 only)

    #pragma unroll
    for (int s = 0; s < KB / KCH; ++s) {
        const int kbase = k0 + s * KCH;

        // A tile: A[i0+row, kbase+col], coalesced along k
        {
            const size_t off = (size_t)(i0 + l_row) * M + kbase + l_c4;
            const float4 are = *(const float4*)(A + off);
            const float4 aim = *(const float4*)(A + MM + off);
            As_re[l_row][l_c4 + 0] = are.x; As_re[l_row][l_c4 + 1] = are.y;
            As_re[l_row][l_c4 + 2] = are.z; As_re[l_row][l_c4 + 3] = are.w;
            As_im[l_row][l_c4 + 0] = aim.x; As_im[l_row][l_c4 + 1] = aim.y;
            As_im[l_row][l_c4 + 2] = aim.z; As_im[l_row][l_c4 + 3] = aim.w;
        }
        // Cb tile with fused p[k] complex scale
        const int k = kbase + l_row;
        const float pre = p1[k];
        const float pim = p1[M + k];
        {
            const size_t off = (size_t)k * M + i0 + l_c4;
            const float4 cre = *(const float4*)(Cb + off);
            const float4 cim = *(const float4*)(Cb + MM + off);
            Cb_re[l_row][l_c4 + 0] = pre * cre.x - pim * cim.x;
            Cb_re[l_row][l_c4 + 1] = pre * cre.y - pim * cim.y;
            Cb_re[l_row][l_c4 + 2] = pre * cre.z - pim * cim.z;
            Cb_re[l_row][l_c4 + 3] = pre * cre.w - pim * cim.w;
            Cb_im[l_row][l_c4 + 0] = pre * cim.x + pim * cre.x;
            Cb_im[l_row][l_c4 + 1] = pre * cim.y + pim * cre.y;
            Cb_im[l_row][l_c4 + 2] = pre * cim.z + pim * cre.z;
            Cb_im[l_row][l_c4 + 3] = pre * cim.w + pim * cre.w;
        }
        if (qset) {   // Cc = C3 tile, same k's, same p scale
            const size_t off = (size_t)k * M + i0 + l_c4;
            const float4 cre = *(const float4*)(C3 + off);
            const float4 cim = *(const float4*)(C3 + MM + off);
            Cc_re[l_row][l_c4 + 0] = pre * cre.x - pim * cim.x;
            Cc_re[l_row][l_c4 + 1] = pre * cre.y - pim * cim.y;
            Cc_re[l_row][l_c4 + 2] = pre * cre.z - pim * cim.z;
            Cc_re[l_row][l_c4 + 3] = pre * cre.w - pim * cim.w;
            Cc_im[l_row][l_c4 + 0] = pre * cim.x + pim * cre.x;
            Cc_im[l_row][l_c4 + 1] = pre * cim.y + pim * cre.y;
            Cc_im[l_row][l_c4 + 2] = pre * cim.z + pim * cre.z;
            Cc_im[l_row][l_c4 + 3] = pre * cim.w + pim * cre.w;
        }
        __syncthreads();

        #pragma unroll
        for (int j = 0; j < 4; ++j) {
            const int kk = (kslice << 2) + j;
            const float a_re = As_re[i_local][kk];
            const float a_im = As_im[i_local][kk];
            {
                const float x_re = Cb_re[kk][i_local];
                const float x_im = Cb_im[kk][i_local];
                b_re += a_re * x_re - a_im * x_im;
                b_im += a_re * x_im + a_im * x_re;
            }
            if (qset) {
                const float x_re = Cc_re[kk][i_local];
                const float x_im = Cc_im[kk][i_local];
                c_re_acc += a_re * x_re - a_im * x_im;
                c_im_acc += a_re * x_im + a_im * x_re;
            }
        }
        __syncthreads();
    }

    red[0][t] = b_re;
    red[1][t] = b_im;
    red[2][t] = c_re_acc;
    red[3][t] = c_im_acc;
    __syncthreads();
    if (t < TI) {
        float s0 = 0.f, s1 = 0.f, s2 = 0.f, s3 = 0.f;
        #pragma unroll
        for (int s = 0; s < 8; ++s) {
            s0 += red[0][t + 32 * s];
            s1 += red[1][t + 32 * s];
            s2 += red[2][t + 32 * s];
            s3 += red[3][t + 32 * s];
        }
        if (qset == 0) {
            D[((size_t)(0 * KSPLIT) + z) * M + i0 + t] = s0;   // Q1 re
            D[((size_t)(1 * KSPLIT) + z) * M + i0 + t] = s1;   // Q1 im
        } else {
            D[((size_t)(2 * KSPLIT) + z) * M + i0 + t] = s0;   // Q2 re
            D[((size_t)(3 * KSPLIT) + z) * M + i0 + t] = s1;   // Q2 im
            D[((size_t)(4 * KSPLIT) + z) * M + i0 + t] = s2;   // Q3 re
            D[((size_t)(5 * KSPLIT) + z) * M + i0 + t] = s3;   // Q3 im
        }
    }
}

// Latency-parallelized finalize: 32 blocks x 256 threads; 8 threads ("parts")
// cooperate per diagonal index i. Each part loads 1-2 of the 11 diag (re,im)
// pairs (stride-(M+1) random lines) + 2 of the 16 KSPLIT partials per Q comp;
// one lane per i does the final arithmetic from LDS. 8x the outstanding-load
// parallelism of the old 8-block version (which was latency-bound).
__global__ __launch_bounds__(256)
void finalize_kernel(const float* __restrict__ Theta,
                     const float* __restrict__ A1, const float* __restrict__ B1, const float* __restrict__ C1,
                     const float* __restrict__ A2, const float* __restrict__ B2, const float* __restrict__ C2,
                     const float* __restrict__ A3, const float* __restrict__ B3, const float* __restrict__ C3,
                     const float* __restrict__ alpha, const float* __restrict__ belta,
                     const float* __restrict__ p2, const float* __restrict__ D,
                     float* __restrict__ out)
{
    __shared__ float vals[22][32];      // [pair_component][i_local]
    __shared__ float qpart[6][8][32];   // [q_comp][part][i_local]

    const int t    = threadIdx.x;
    const int il   = t & 31;            // i_local
    const int part = t >> 5;            // 0..7
    const int i    = blockIdx.x * 32 + il;
    const size_t MM = (size_t)M * M;
    const size_t dg = (size_t)i * M + i;

    // D partial sums: part p covers z = 2p, 2p+1 (coalesced: il consecutive)
    #pragma unroll
    for (int qc = 0; qc < 6; ++qc) {
        const size_t b0 = ((size_t)qc * KSPLIT + 2 * part) * M + i;
        qpart[qc][part][il] = D[b0] + D[b0 + M];
    }

    // diag pairs 0..7: Theta,A1,B1,C1,A2,B2,C2,A3 -> part 0..7
    const float* bsel = part == 0 ? Theta : part == 1 ? A1 : part == 2 ? B1 :
                        part == 3 ? C1    : part == 4 ? A2 : part == 5 ? B2 :
                        part == 6 ? C2    : A3;
    vals[2 * part + 0][il] = bsel[dg];
    vals[2 * part + 1][il] = bsel[MM + dg];
    // diag pairs 8..10: B3,C3,p2 -> parts 0..2
    if (part < 3) {
        const float* esel = part == 0 ? B3 : part == 1 ? C3 : p2;
        const size_t o0 = (part == 2) ? (size_t)i       : dg;
        const size_t o1 = (part == 2) ? (size_t)(M + i) : MM + dg;
        vals[16 + 2 * part][il] = esel[o0];
        vals[17 + 2 * part][il] = esel[o1];
    }
    __syncthreads();

    if (t < 32) {   // one lane per i: all operands now LDS-resident
        float qs[6];
        #pragma unroll
        for (int qc = 0; qc < 6; ++qc) {
            float s = 0.f;
            #pragma unroll
            for (int p = 0; p < 8; ++p) s += qpart[qc][p][t];
            qs[qc] = s;
        }

        const float th_re = vals[0][t],  th_im = vals[1][t];
        const float a1re  = vals[2][t],  a1im  = vals[3][t];
        const float b1re  = vals[4][t],  b1im  = vals[5][t];
        const float c1re  = vals[6][t],  c1im  = vals[7][t];
        const float a2re  = vals[8][t],  a2im  = vals[9][t];
        const float b2re  = vals[10][t], b2im  = vals[11][t];
        const float c2re  = vals[12][t], c2im  = vals[13][t];
        const float a3re  = vals[14][t], a3im  = vals[15][t];
        const float b3re  = vals[16][t], b3im  = vals[17][t];
        const float c3re  = vals[18][t], c3im  = vals[19][t];
        const float p2re  = vals[20][t], p2im  = vals[21][t];

        const float al = alpha[0], be = belta[0];

        float b_re = p2re, b_im = p2im;
        {   // b1 = alpha * dA1 *c (Th *c dC1) - diagQ1 + dB1
            const float t_re = th_re * c1re - th_im * c1im;
            const float t_im = th_re * c1im + th_im * c1re;
            b_re += al * (a1re * t_re - a1im * t_im) - qs[0] + b1re;
            b_im += al * (a1re * t_im + a1im * t_re) - qs[1] + b1im;
        }
        {   // b2
            const float t_re = th_re * c2re - th_im * c2im;
            const float t_im = th_re * c2im + th_im * c2re;
            b_re += be * (a2re * t_re - a2im * t_im) - qs[2] + b2re;
            b_im += be * (a2re * t_im + a2im * t_re) - qs[3] + b2im;
        }
        {   // b3 (diag uses A3/C3/B3; Q3 used A2 upstream per reference)
            const float t_re = th_re * c3re - th_im * c3im;
            const float t_im = th_re * c3im + th_im * c3re;
            b_re += be * (a3re * t_re - a3im * t_im) - qs[4] + b3re;
            b_im += be * (a3re * t_im + a3im * t_re) - qs[5] + b3im;
        }

        const float inv = 1.0f / sqrtf(b_re * b_re + b_im * b_im);
        out[dg]      = b_re * inv;   // for t<32, part==0 so dg is this i's diag
        out[MM + dg] = b_im * inv;
    }
}

extern "C" void kernel_launch(void* const* d_in, const int* in_sizes, int n_in,
                              void* d_out, int out_size, void* d_ws, size_t ws_size,
                              hipStream_t stream) {
    const float* Theta = (const float*)d_in[0];
    const float* A1    = (const float*)d_in[1];
    const float* B1    = (const float*)d_in[2];
    const float* C1    = (const float*)d_in[3];
    const float* A2    = (const float*)d_in[4];
    const float* B2    = (const float*)d_in[5];
    const float* C2    = (const float*)d_in[6];
    const float* A3    = (const float*)d_in[7];
    const float* B3    = (const float*)d_in[8];
    const float* C3    = (const float*)d_in[9];
    const float* alpha = (const float*)d_in[10];
    const float* belta = (const float*)d_in[11];
    const float* p1    = (const float*)d_in[12];
    const float* p2    = (const float*)d_in[13];
    float* out = (float*)d_out;
    float* D   = (float*)d_ws;   // [6][16][1024] floats, fully written by diagq

    dim3 grid(M / TI, 2, KSPLIT);   // 32 x 2 x 16 = 1024 blocks
    diagq_kernel<<<grid, 256, 0, stream>>>(A1, C1, A2, C2, C3, p1, D, out);

    finalize_kernel<<<dim3(M / 32), 256, 0, stream>>>(
        Theta, A1, B1, C1, A2, B2, C2, A3, B3, C3, alpha, belta, p2, D, out);
}